// Round 3
// baseline (772.497 us; speedup 1.0000x reference)
//
#include <hip/hip_runtime.h>
#include <stdint.h>

#define B_ 4
#define S_ 2048
#define D_ 256
#define NH_ 12
#define M_ (B_*S_)      // 8192 rows of flattened input
#define J_ (NH_*D_)     // 3072 projection cols

typedef __bf16 bf16;
typedef __bf16 bf16x8 __attribute__((ext_vector_type(8)));
typedef __bf16 bf16x4 __attribute__((ext_vector_type(4)));
typedef float  f32x4  __attribute__((ext_vector_type(4)));

#define MFMA16(a,b,c) __builtin_amdgcn_mfma_f32_16x16x32_bf16(a,b,c,0,0,0)

__device__ __forceinline__ void g2lds16(void* l, const void* g) {
  __builtin_amdgcn_global_load_lds(
      (const __attribute__((address_space(1))) unsigned int*)g,
      (__attribute__((address_space(3))) unsigned int*)l, 16, 0, 0);
}

// ---------------- X fp32 -> bf16 ----------------
__global__ __launch_bounds__(256) void cvt_x(const float* __restrict__ in,
                                             bf16* __restrict__ out) {
  int i = blockIdx.x * 256 + threadIdx.x;
  f32x4 v = *(const f32x4*)(in + (size_t)i * 4);
  bf16x4 o;
#pragma unroll
  for (int k = 0; k < 4; ++k) o[k] = (bf16)v[k];
  *(bf16x4*)(out + (size_t)i * 4) = o;
}

// ---------------- weight transpose+cvt: W fp32 [256][3072] -> Wt bf16 [3072][256] ----------------
__global__ __launch_bounds__(256) void transpose_w(const float* __restrict__ W,
                                                   bf16* __restrict__ Wt) {
  int j  = blockIdx.x * 256 + threadIdx.x;   // 0..3071, coalesced reads over j
  int c0 = blockIdx.y * 16;
  bf16x8 v0, v1;
#pragma unroll
  for (int i = 0; i < 8; ++i) v0[i] = (bf16)W[(size_t)(c0 + i) * J_ + j];
#pragma unroll
  for (int i = 0; i < 8; ++i) v1[i] = (bf16)W[(size_t)(c0 + 8 + i) * J_ + j];
  *(bf16x8*)(Wt + (size_t)j * D_ + c0)     = v0;
  *(bf16x8*)(Wt + (size_t)j * D_ + c0 + 8) = v1;
}

// ---------------- mask tile flags: 1 if 64x64 tile is all ones ----------------
__global__ __launch_bounds__(256) void mask_flags_k(const int* __restrict__ mask,
                                                    int* __restrict__ flags) {
  int bx = blockIdx.x;                 // b*1024 + st*32 + ft
  int ft = bx & 31, st = (bx >> 5) & 31, b = bx >> 10;
  int t = threadIdx.x;
  const int4* mp4 = (const int4*)(mask + (size_t)b * S_ * S_ +
                                  (size_t)(st * 64 + (t >> 2)) * S_ + ft * 64 + (t & 3) * 16);
  bool ok = true;
#pragma unroll
  for (int i = 0; i < 4; ++i) {
    int4 v = mp4[i];
    ok &= (v.x == 1) & (v.y == 1) & (v.z == 1) & (v.w == 1);
  }
  __shared__ int flag;
  if (t == 0) flag = 1;
  __syncthreads();
  if (!ok) flag = 0;                   // benign race, all write 0
  __syncthreads();
  if (t == 0) flags[bx] = flag;
}

// ---------------- GEMM: C[M][N] = A[M][256] * Bm[N][256]^T + bias ----------------
// m97 structure: 128x128 tile, BK=32, 4 waves each 64x64. Plain row-major LDS
// (lane l of wave w lands at base + w*1024B + l*16B).
__global__ __launch_bounds__(256) void gemm_bt(
    const bf16* __restrict__ A, const bf16* __restrict__ Bm,
    const float* __restrict__ bias, bf16* __restrict__ C,
    int Ndim, int bias_mode)
{
  __shared__ bf16 As[128 * 32];
  __shared__ bf16 Bs[128 * 32];
  const int nbn = Ndim >> 7;
  const int bm = blockIdx.x / nbn, bn = blockIdx.x % nbn;
  const int t = threadIdx.x, w = t >> 6, l = t & 63;
  const int lane16 = l & 15, quad = l >> 4;
  const int wm = (w & 1) << 6, wn = (w >> 1) << 6;
  // staging: thread t covers LDS row t>>2, k-chunk t&3 (plain layout)
  const bf16* Ag = A + (size_t)(bm << 7) * 256 + (size_t)(t >> 2) * 256 + (t & 3) * 8;
  const bf16* Bg = Bm + (size_t)(bn << 7) * 256 + (size_t)(t >> 2) * 256 + (t & 3) * 8;
  f32x4 acc[4][4] = {};
  for (int kt = 0; kt < 256; kt += 32) {
    __syncthreads();
    g2lds16(As + (w << 9),        Ag + kt);
    g2lds16(As + 2048 + (w << 9), Ag + (size_t)64 * 256 + kt);
    g2lds16(Bs + (w << 9),        Bg + kt);
    g2lds16(Bs + 2048 + (w << 9), Bg + (size_t)64 * 256 + kt);
    __syncthreads();
    bf16x8 af[4], bfr[4];
#pragma unroll
    for (int i = 0; i < 4; ++i)
      af[i] = *(const bf16x8*)(As + (wm + i * 16 + lane16) * 32 + quad * 8);
#pragma unroll
    for (int i = 0; i < 4; ++i)
      bfr[i] = *(const bf16x8*)(Bs + (wn + i * 16 + lane16) * 32 + quad * 8);
#pragma unroll
    for (int i = 0; i < 4; ++i)
#pragma unroll
      for (int jx = 0; jx < 4; ++jx)
        acc[i][jx] = MFMA16(af[i], bfr[jx], acc[i][jx]);
  }
#pragma unroll
  for (int i = 0; i < 4; ++i)
#pragma unroll
    for (int jx = 0; jx < 4; ++jx) {
      int col = (bn << 7) + wn + jx * 16 + lane16;
#pragma unroll
      for (int r = 0; r < 4; ++r) {
        int row = (bm << 7) + wm + i * 16 + quad * 4 + r;
        float v = acc[i][jx][r] + (bias_mode ? bias[row] : bias[col]);
        C[(size_t)row * Ndim + col] = (bf16)v;
      }
    }
}

// ---------------- fused attention ----------------
// grid: b*384 + n*32 + st.  Block: 4 waves, each owns 16 s-rows (BM=64), f-tile BN=32.
// Q (bf16 copy of input) in regs; K tile [32f][256d], Vt tile [256d][32f], P [16s][32f] in LDS.
__global__ __launch_bounds__(256) void attn_k(
    const bf16* __restrict__ X, const bf16* __restrict__ QK, const bf16* __restrict__ Vt,
    const int* __restrict__ mask, const int* __restrict__ flags,
    float* __restrict__ Oacc)
{
  __shared__ bf16 Ks[32 * 256];
  __shared__ bf16 Vs[256 * 32];
  __shared__ bf16 Ps[4][16 * 32];
  const int bx = blockIdx.x;
  const int st = bx & 31, n = (bx >> 5) % NH_, b = bx / (32 * NH_);
  const int t = threadIdx.x, w = t >> 6, l = t & 63;
  const int lane16 = l & 15, quad = l >> 4;
  const int sw = (st << 6) + (w << 4);          // wave's first s row
  const bf16* Xb = X + (size_t)b * S_ * D_;
  bf16x8 qf[8];                                  // Q A-frags: 16 rows x 256 k
#pragma unroll
  for (int kt = 0; kt < 8; ++kt)
    qf[kt] = *(const bf16x8*)(Xb + (size_t)(sw + lane16) * D_ + kt * 32 + quad * 8);
  const bf16* QKb = QK + (size_t)b * S_ * J_ + n * D_;
  const bf16* Vtb = Vt + (size_t)n * D_ * M_ + (size_t)b * S_;
  const int* flagb = flags + (b * 32 + st) * 32;
  f32x4 oacc[16] = {};
  float lsum[4] = {0.f, 0.f, 0.f, 0.f};

  for (int f0 = 0; f0 < S_; f0 += 32) {
    __syncthreads();
    // K tile: LDS row = f (512B rows). Thread t covers row i*8+(t>>5), d-chunk t&31.
#pragma unroll
    for (int i = 0; i < 4; ++i) {
      int frow = i * 8 + (t >> 5);
      g2lds16(Ks + i * 2048 + (w << 9), QKb + (size_t)(f0 + frow) * J_ + (t & 31) * 8);
    }
    // Vt tile: LDS row = d (64B rows). Thread t covers row i*64+(t>>2), f-chunk t&3.
#pragma unroll
    for (int i = 0; i < 4; ++i) {
      int drow = i * 64 + (t >> 2);
      g2lds16(Vs + i * 2048 + (w << 9), Vtb + (size_t)drow * M_ + f0 + (t & 3) * 8);
    }
    __syncthreads();
    // S = Q K^T : 16 x 32
    f32x4 sfr[2] = {};
#pragma unroll
    for (int kt = 0; kt < 8; ++kt)
#pragma unroll
      for (int ct = 0; ct < 2; ++ct) {
        int fl = ct * 16 + lane16;
        bf16x8 kf = *(const bf16x8*)(Ks + fl * 256 + kt * 32 + quad * 8);
        sfr[ct] = MFMA16(qf[kt], kf, sfr[ct]);
      }
    // mask + exp (no max-subtraction: |S| <~ 40, fp32 exp safe)
    float ex[2][4];
    if (flagb[f0 >> 6]) {
#pragma unroll
      for (int ct = 0; ct < 2; ++ct)
#pragma unroll
        for (int r = 0; r < 4; ++r) ex[ct][r] = __expf(sfr[ct][r]);
    } else {
#pragma unroll
      for (int ct = 0; ct < 2; ++ct)
#pragma unroll
        for (int r = 0; r < 4; ++r) {
          int s = sw + quad * 4 + r, f = f0 + ct * 16 + lane16;
          float add = (1.0f - (float)mask[(size_t)b * S_ * S_ + (size_t)s * S_ + f]) * -10000.0f;
          ex[ct][r] = __expf(sfr[ct][r] + add);
        }
    }
    // row sums (row s=quad*4+r lives across the quad's 16 contiguous lanes)
#pragma unroll
    for (int r = 0; r < 4; ++r) {
      float rs = ex[0][r] + ex[1][r];
      rs += __shfl_xor(rs, 1, 16);
      rs += __shfl_xor(rs, 2, 16);
      rs += __shfl_xor(rs, 4, 16);
      rs += __shfl_xor(rs, 8, 16);
      lsum[r] += rs;
    }
    // P -> LDS (C-layout -> A-layout round trip), plain [s][f]
#pragma unroll
    for (int ct = 0; ct < 2; ++ct)
#pragma unroll
      for (int r = 0; r < 4; ++r) {
        int s = quad * 4 + r, f = ct * 16 + lane16;
        Ps[w][s * 32 + f] = (bf16)ex[ct][r];
      }
    __syncthreads();
    // O += P * V  (A = P[s][f], B = Vt[d][f])
    bf16x8 pf = *(const bf16x8*)(&Ps[w][lane16 * 32 + quad * 8]);
#pragma unroll
    for (int nt = 0; nt < 16; ++nt) {
      int dl = nt * 16 + lane16;
      bf16x8 vf = *(const bf16x8*)(Vs + dl * 32 + quad * 8);
      oacc[nt] = MFMA16(pf, vf, oacc[nt]);
    }
  }
  // normalize and head-sum into fp32 output
  float* Ob = Oacc + (size_t)b * S_ * D_;
  float inv[4];
#pragma unroll
  for (int r = 0; r < 4; ++r) inv[r] = 1.0f / lsum[r];
#pragma unroll
  for (int nt = 0; nt < 16; ++nt) {
    int d = nt * 16 + lane16;
#pragma unroll
    for (int r = 0; r < 4; ++r) {
      int s = sw + quad * 4 + r;
      unsafeAtomicAdd(&Ob[(size_t)s * D_ + d], oacc[nt][r] * inv[r]);
    }
  }
}

extern "C" void kernel_launch(void* const* d_in, const int* in_sizes, int n_in,
                              void* d_out, int out_size, void* d_ws, size_t ws_size,
                              hipStream_t stream) {
  (void)in_sizes; (void)n_in; (void)out_size; (void)ws_size;
  const float* X    = (const float*)d_in[0];   // fp32 per reference
  const int*   mask = (const int*)d_in[1];
  const float* Wqk  = (const float*)d_in[2];
  const float* bqk  = (const float*)d_in[3];
  const float* Wv   = (const float*)d_in[4];
  const float* bv   = (const float*)d_in[5];
  float* out = (float*)d_out;                  // fp32 per reference output

  char* p = (char*)d_ws;
  bf16*  Xbf  = (bf16*)p;  p += (size_t)M_ * D_ * 2;      // 4.2 MB
  bf16*  Wqkt = (bf16*)p;  p += (size_t)J_ * D_ * 2;      // 1.5 MB
  bf16*  Wvt  = (bf16*)p;  p += (size_t)J_ * D_ * 2;      // 1.5 MB
  bf16*  QKw  = (bf16*)p;  p += (size_t)M_ * J_ * 2;      // 50.3 MB  [m][j]
  bf16*  Vtw  = (bf16*)p;  p += (size_t)J_ * M_ * 2;      // 50.3 MB  [j][m]
  int*   flags= (int*)p;   p += 4096 * 4;

  hipMemsetAsync(out, 0, (size_t)M_ * D_ * 4, stream);    // we accumulate into out
  cvt_x<<<(M_ * D_) / (256 * 4), 256, 0, stream>>>(X, Xbf);
  transpose_w<<<dim3(12, 16), 256, 0, stream>>>(Wqk, Wqkt);
  transpose_w<<<dim3(12, 16), 256, 0, stream>>>(Wv, Wvt);
  mask_flags_k<<<4096, 256, 0, stream>>>(mask, flags);
  gemm_bt<<<(M_ / 128) * (J_ / 128), 256, 0, stream>>>(Xbf, Wqkt, bqk, QKw, J_, 0);
  gemm_bt<<<(J_ / 128) * (M_ / 128), 256, 0, stream>>>(Wvt, Xbf, bv, Vtw, M_, 1);
  attn_k<<<B_ * NH_ * (S_ / 64), 256, 0, stream>>>(Xbf, QKw, Vtw, mask, flags, out);
}

// Round 4
// 633.237 us; speedup vs baseline: 1.2199x; 1.2199x over previous
//
#include <hip/hip_runtime.h>
#include <stdint.h>

#define B_ 4
#define S_ 2048
#define D_ 256
#define NH_ 12
#define M_ (B_*S_)      // 8192 rows of flattened input
#define J_ (NH_*D_)     // 3072 projection cols

typedef __bf16 bf16;
typedef __bf16 bf16x8 __attribute__((ext_vector_type(8)));
typedef __bf16 bf16x4 __attribute__((ext_vector_type(4)));
typedef float  f32x4  __attribute__((ext_vector_type(4)));

#define MFMA16(a,b,c) __builtin_amdgcn_mfma_f32_16x16x32_bf16(a,b,c,0,0,0)

__device__ __forceinline__ void g2lds16(void* l, const void* g) {
  __builtin_amdgcn_global_load_lds(
      (const __attribute__((address_space(1))) unsigned int*)g,
      (__attribute__((address_space(3))) unsigned int*)l, 16, 0, 0);
}

// ---------------- X fp32 -> bf16 ----------------
__global__ __launch_bounds__(256) void cvt_x(const float* __restrict__ in,
                                             bf16* __restrict__ out) {
  int i = blockIdx.x * 256 + threadIdx.x;
  f32x4 v = *(const f32x4*)(in + (size_t)i * 4);
  bf16x4 o;
#pragma unroll
  for (int k = 0; k < 4; ++k) o[k] = (bf16)v[k];
  *(bf16x4*)(out + (size_t)i * 4) = o;
}

// ---------------- weight transpose+cvt: W fp32 [256][3072] -> Wt bf16 [3072][256] ----------------
__global__ __launch_bounds__(256) void transpose_w(const float* __restrict__ W,
                                                   bf16* __restrict__ Wt) {
  int j  = blockIdx.x * 256 + threadIdx.x;   // 0..3071, coalesced reads over j
  int c0 = blockIdx.y * 16;
  bf16x8 v0, v1;
#pragma unroll
  for (int i = 0; i < 8; ++i) v0[i] = (bf16)W[(size_t)(c0 + i) * J_ + j];
#pragma unroll
  for (int i = 0; i < 8; ++i) v1[i] = (bf16)W[(size_t)(c0 + 8 + i) * J_ + j];
  *(bf16x8*)(Wt + (size_t)j * D_ + c0)     = v0;
  *(bf16x8*)(Wt + (size_t)j * D_ + c0 + 8) = v1;
}

// ---------------- mask tile flags: 1 if 64x64 tile is all ones ----------------
__global__ __launch_bounds__(256) void mask_flags_k(const int* __restrict__ mask,
                                                    int* __restrict__ flags) {
  int bx = blockIdx.x;                 // b*1024 + st*32 + ft
  int ft = bx & 31, st = (bx >> 5) & 31, b = bx >> 10;
  int t = threadIdx.x;
  const int4* mp4 = (const int4*)(mask + (size_t)b * S_ * S_ +
                                  (size_t)(st * 64 + (t >> 2)) * S_ + ft * 64 + (t & 3) * 16);
  bool ok = true;
#pragma unroll
  for (int i = 0; i < 4; ++i) {
    int4 v = mp4[i];
    ok &= (v.x == 1) & (v.y == 1) & (v.z == 1) & (v.w == 1);
  }
  __shared__ int flag;
  if (t == 0) flag = 1;
  __syncthreads();
  if (!ok) flag = 0;                   // benign race, all write 0
  __syncthreads();
  if (t == 0) flags[bx] = flag;
}

// ---------------- GEMM: C[M][N] = A[M][256] * Bm[N][256]^T + bias ----------------
// 128x128 tile, BK=32, 4 waves each 64x64. XOR k-chunk swizzle (verified algebra):
// LDS slot (row=t>>2, sc=t&3) holds global chunk gc=(sc-(row>>1))&3; read slot
// for global chunk quad at row r is ((quad+(r>>1))&3) -> 2-way banks (free).
__global__ __launch_bounds__(256) void gemm_bt(
    const bf16* __restrict__ A, const bf16* __restrict__ Bm,
    const float* __restrict__ bias, bf16* __restrict__ C,
    int Ndim, int bias_mode)
{
  __shared__ bf16 As[128 * 32];
  __shared__ bf16 Bs[128 * 32];
  const int nbn = Ndim >> 7;
  const int bm = blockIdx.x / nbn, bn = blockIdx.x % nbn;
  const int t = threadIdx.x, w = t >> 6, l = t & 63;
  const int lane16 = l & 15, quad = l >> 4;
  const int wm = (w & 1) << 6, wn = (w >> 1) << 6;
  const int gc = ((t & 3) - (t >> 3)) & 3;
  const bf16* Ag = A + (size_t)(bm << 7) * 256 + (size_t)(t >> 2) * 256 + gc * 8;
  const bf16* Bg = Bm + (size_t)(bn << 7) * 256 + (size_t)(t >> 2) * 256 + gc * 8;
  const int rslot = ((quad + (lane16 >> 1)) & 3) * 8;
  f32x4 acc[4][4] = {};
  for (int kt = 0; kt < 256; kt += 32) {
    __syncthreads();
    g2lds16(As + (w << 9),        Ag + kt);
    g2lds16(As + 2048 + (w << 9), Ag + (size_t)64 * 256 + kt);
    g2lds16(Bs + (w << 9),        Bg + kt);
    g2lds16(Bs + 2048 + (w << 9), Bg + (size_t)64 * 256 + kt);
    __syncthreads();
    bf16x8 af[4], bfr[4];
#pragma unroll
    for (int i = 0; i < 4; ++i)
      af[i] = *(const bf16x8*)(As + (wm + i * 16 + lane16) * 32 + rslot);
#pragma unroll
    for (int i = 0; i < 4; ++i)
      bfr[i] = *(const bf16x8*)(Bs + (wn + i * 16 + lane16) * 32 + rslot);
#pragma unroll
    for (int i = 0; i < 4; ++i)
#pragma unroll
      for (int jx = 0; jx < 4; ++jx)
        acc[i][jx] = MFMA16(af[i], bfr[jx], acc[i][jx]);
  }
#pragma unroll
  for (int i = 0; i < 4; ++i)
#pragma unroll
    for (int jx = 0; jx < 4; ++jx) {
      int col = (bn << 7) + wn + jx * 16 + lane16;
#pragma unroll
      for (int r = 0; r < 4; ++r) {
        int row = (bm << 7) + wm + i * 16 + quad * 4 + r;
        float v = acc[i][jx][r] + (bias_mode ? bias[row] : bias[col]);
        C[(size_t)row * Ndim + col] = (bf16)v;
      }
    }
}

// ---------------- fused attention ----------------
// grid: b*384 + n*32 + st.  Block: 4 waves, each owns 16 s-rows (BM=64), f-tile BN=32.
// Q in regs; K tile [32f][256d] (8-slot XOR swizzle), Vt tile [256d][32f] (4-slot XOR
// swizzle), P [16s][40] padded rows. All LDS accesses <=2-way except P-writes (4-way).
__global__ __launch_bounds__(256, 4) void attn_k(
    const bf16* __restrict__ X, const bf16* __restrict__ QK, const bf16* __restrict__ Vt,
    const int* __restrict__ mask, const int* __restrict__ flags,
    float* __restrict__ Oacc)
{
  __shared__ bf16 Ks[32 * 256];
  __shared__ bf16 Vs[256 * 32];
  __shared__ bf16 Ps[4][16 * 40];
  const int bx = blockIdx.x;
  const int st = bx & 31, n = (bx >> 5) % NH_, b = bx / (32 * NH_);
  const int t = threadIdx.x, w = t >> 6, l = t & 63;
  const int lane16 = l & 15, quad = l >> 4;
  const int sw = (st << 6) + (w << 4);          // wave's first s row
  const bf16* Xb = X + (size_t)b * S_ * D_;
  bf16x8 qf[8];                                  // Q A-frags: 16 rows x 256 k
#pragma unroll
  for (int kt = 0; kt < 8; ++kt)
    qf[kt] = *(const bf16x8*)(Xb + (size_t)(sw + lane16) * D_ + kt * 32 + quad * 8);
  const bf16* QKb = QK + (size_t)b * S_ * J_ + n * D_;
  const bf16* Vtb = Vt + (size_t)n * D_ * M_ + (size_t)b * S_;
  const int* flagb = flags + (b * 32 + st) * 32;
  f32x4 oacc[16] = {};
  float lsum[4] = {0.f, 0.f, 0.f, 0.f};

  for (int f0 = 0; f0 < S_; f0 += 32) {
    __syncthreads();
    // K tile: LDS row=f (512B). Slot chunk l&31 holds global d-chunk (l&31)^(frow&7).
#pragma unroll
    for (int i = 0; i < 4; ++i) {
      int frow = i * 8 + (t >> 5);
      int dc = (t & 31) ^ (frow & 7);
      g2lds16(Ks + i * 2048 + (w << 9), QKb + (size_t)(f0 + frow) * J_ + dc * 8);
    }
    // Vt tile: LDS row=d (64B). Slot chunk l&3 holds global f-chunk (l&3)^((drow>>1)&3).
#pragma unroll
    for (int i = 0; i < 4; ++i) {
      int drow = i * 64 + (t >> 2);
      int fc = (t & 3) ^ ((drow >> 1) & 3);
      g2lds16(Vs + i * 2048 + (w << 9), Vtb + (size_t)drow * M_ + f0 + fc * 8);
    }
    __syncthreads();
    // S = Q K^T : 16 x 32
    f32x4 sfr[2] = {};
#pragma unroll
    for (int kt = 0; kt < 8; ++kt)
#pragma unroll
      for (int ct = 0; ct < 2; ++ct) {
        int fl = ct * 16 + lane16;
        bf16x8 kf = *(const bf16x8*)(Ks + fl * 256 + (((kt * 4 + quad) ^ (fl & 7)) * 8));
        sfr[ct] = MFMA16(qf[kt], kf, sfr[ct]);
      }
    // mask + exp (no max-subtraction: |S| <~ 40, fp32 exp safe)
    float ex[2][4];
    if (flagb[f0 >> 6]) {
#pragma unroll
      for (int ct = 0; ct < 2; ++ct)
#pragma unroll
        for (int r = 0; r < 4; ++r) ex[ct][r] = __expf(sfr[ct][r]);
    } else {
#pragma unroll
      for (int ct = 0; ct < 2; ++ct)
#pragma unroll
        for (int r = 0; r < 4; ++r) {
          int s = sw + quad * 4 + r, f = f0 + ct * 16 + lane16;
          float add = (1.0f - (float)mask[(size_t)b * S_ * S_ + (size_t)s * S_ + f]) * -10000.0f;
          ex[ct][r] = __expf(sfr[ct][r] + add);
        }
    }
    // row sums (row s=quad*4+r lives across the quad's 16 contiguous lanes)
#pragma unroll
    for (int r = 0; r < 4; ++r) {
      float rs = ex[0][r] + ex[1][r];
      rs += __shfl_xor(rs, 1, 16);
      rs += __shfl_xor(rs, 2, 16);
      rs += __shfl_xor(rs, 4, 16);
      rs += __shfl_xor(rs, 8, 16);
      lsum[r] += rs;
    }
    // P -> LDS (C-layout -> A-layout), rows padded to 40 elems (80B: 2-way b128 reads)
#pragma unroll
    for (int ct = 0; ct < 2; ++ct)
#pragma unroll
      for (int r = 0; r < 4; ++r) {
        int s = quad * 4 + r, f = ct * 16 + lane16;
        Ps[w][s * 40 + f] = (bf16)ex[ct][r];
      }
    // NO barrier here: Ps is wave-private; lgkmcnt ordering suffices.
    // O += P * V  (A = P[s][f], B = Vt[d][f])
    bf16x8 pf = *(const bf16x8*)(&Ps[w][lane16 * 40 + quad * 8]);
#pragma unroll
    for (int nt = 0; nt < 16; ++nt) {
      int dl = nt * 16 + lane16;
      bf16x8 vf = *(const bf16x8*)(Vs + dl * 32 + ((quad ^ ((dl >> 1) & 3)) * 8));
      oacc[nt] = MFMA16(pf, vf, oacc[nt]);
    }
  }
  // normalize and head-sum into fp32 output
  float* Ob = Oacc + (size_t)b * S_ * D_;
  float inv[4];
#pragma unroll
  for (int r = 0; r < 4; ++r) inv[r] = 1.0f / lsum[r];
#pragma unroll
  for (int nt = 0; nt < 16; ++nt) {
    int d = nt * 16 + lane16;
#pragma unroll
    for (int r = 0; r < 4; ++r) {
      int s = sw + quad * 4 + r;
      unsafeAtomicAdd(&Ob[(size_t)s * D_ + d], oacc[nt][r] * inv[r]);
    }
  }
}

extern "C" void kernel_launch(void* const* d_in, const int* in_sizes, int n_in,
                              void* d_out, int out_size, void* d_ws, size_t ws_size,
                              hipStream_t stream) {
  (void)in_sizes; (void)n_in; (void)out_size; (void)ws_size;
  const float* X    = (const float*)d_in[0];   // fp32 per reference
  const int*   mask = (const int*)d_in[1];
  const float* Wqk  = (const float*)d_in[2];
  const float* bqk  = (const float*)d_in[3];
  const float* Wv   = (const float*)d_in[4];
  const float* bv   = (const float*)d_in[5];
  float* out = (float*)d_out;                  // fp32 per reference output

  char* p = (char*)d_ws;
  bf16*  Xbf  = (bf16*)p;  p += (size_t)M_ * D_ * 2;      // 4.2 MB
  bf16*  Wqkt = (bf16*)p;  p += (size_t)J_ * D_ * 2;      // 1.5 MB
  bf16*  Wvt  = (bf16*)p;  p += (size_t)J_ * D_ * 2;      // 1.5 MB
  bf16*  QKw  = (bf16*)p;  p += (size_t)M_ * J_ * 2;      // 50.3 MB  [m][j]
  bf16*  Vtw  = (bf16*)p;  p += (size_t)J_ * M_ * 2;      // 50.3 MB  [j][m]
  int*   flags= (int*)p;   p += 4096 * 4;

  hipMemsetAsync(out, 0, (size_t)M_ * D_ * 4, stream);    // we accumulate into out
  cvt_x<<<(M_ * D_) / (256 * 4), 256, 0, stream>>>(X, Xbf);
  transpose_w<<<dim3(12, 16), 256, 0, stream>>>(Wqk, Wqkt);
  transpose_w<<<dim3(12, 16), 256, 0, stream>>>(Wv, Wvt);
  mask_flags_k<<<4096, 256, 0, stream>>>(mask, flags);
  gemm_bt<<<(M_ / 128) * (J_ / 128), 256, 0, stream>>>(Xbf, Wqkt, bqk, QKw, J_, 0);
  gemm_bt<<<(J_ / 128) * (M_ / 128), 256, 0, stream>>>(Wvt, Xbf, bv, Vtw, M_, 1);
  attn_k<<<B_ * NH_ * (S_ / 64), 256, 0, stream>>>(Xbf, QKw, Vtw, mask, flags, out);
}

// Round 5
// 600.334 us; speedup vs baseline: 1.2868x; 1.0548x over previous
//
#include <hip/hip_runtime.h>
#include <stdint.h>

#define B_ 4
#define S_ 2048
#define D_ 256
#define NH_ 12
#define M_ (B_*S_)      // 8192 rows of flattened input
#define J_ (NH_*D_)     // 3072 projection cols

typedef __bf16 bf16;
typedef __bf16 bf16x8 __attribute__((ext_vector_type(8)));
typedef __bf16 bf16x4 __attribute__((ext_vector_type(4)));
typedef float  f32x4  __attribute__((ext_vector_type(4)));

#define MFMA16(a,b,c) __builtin_amdgcn_mfma_f32_16x16x32_bf16(a,b,c,0,0,0)

__device__ __forceinline__ void g2lds16(void* l, const void* g) {
  __builtin_amdgcn_global_load_lds(
      (const __attribute__((address_space(1))) unsigned int*)g,
      (__attribute__((address_space(3))) unsigned int*)l, 16, 0, 0);
}

// ---------------- X fp32 -> bf16 ----------------
__global__ __launch_bounds__(256) void cvt_x(const float* __restrict__ in,
                                             bf16* __restrict__ out) {
  int i = blockIdx.x * 256 + threadIdx.x;
  f32x4 v = *(const f32x4*)(in + (size_t)i * 4);
  bf16x4 o;
#pragma unroll
  for (int k = 0; k < 4; ++k) o[k] = (bf16)v[k];
  *(bf16x4*)(out + (size_t)i * 4) = o;
}

// ---------------- weight transpose+cvt: W fp32 [256][3072] -> Wt bf16 [3072][256] ----------------
__global__ __launch_bounds__(256) void transpose_w(const float* __restrict__ W,
                                                   bf16* __restrict__ Wt) {
  int j  = blockIdx.x * 256 + threadIdx.x;   // 0..3071, coalesced reads over j
  int c0 = blockIdx.y * 16;
  bf16x8 v0, v1;
#pragma unroll
  for (int i = 0; i < 8; ++i) v0[i] = (bf16)W[(size_t)(c0 + i) * J_ + j];
#pragma unroll
  for (int i = 0; i < 8; ++i) v1[i] = (bf16)W[(size_t)(c0 + 8 + i) * J_ + j];
  *(bf16x8*)(Wt + (size_t)j * D_ + c0)     = v0;
  *(bf16x8*)(Wt + (size_t)j * D_ + c0 + 8) = v1;
}

// ---------------- mask tile flags: 1 if 64x64 tile is all ones ----------------
__global__ __launch_bounds__(256) void mask_flags_k(const int* __restrict__ mask,
                                                    int* __restrict__ flags) {
  int bx = blockIdx.x;                 // b*1024 + st*32 + ft
  int ft = bx & 31, st = (bx >> 5) & 31, b = bx >> 10;
  int t = threadIdx.x;
  const int4* mp4 = (const int4*)(mask + (size_t)b * S_ * S_ +
                                  (size_t)(st * 64 + (t >> 2)) * S_ + ft * 64 + (t & 3) * 16);
  bool ok = true;
#pragma unroll
  for (int i = 0; i < 4; ++i) {
    int4 v = mp4[i];
    ok &= (v.x == 1) & (v.y == 1) & (v.z == 1) & (v.w == 1);
  }
  __shared__ int flag;
  if (t == 0) flag = 1;
  __syncthreads();
  if (!ok) flag = 0;                   // benign race, all write 0
  __syncthreads();
  if (t == 0) flags[bx] = flag;
}

// ---------------- GEMM: C[M][N] = A[M][256] * Bm[N][256]^T + bias ----------------
// 128x128 tile, BK=32, 4 waves each 64x64. XOR k-chunk swizzle -> 2-way banks (free).
__global__ __launch_bounds__(256) void gemm_bt(
    const bf16* __restrict__ A, const bf16* __restrict__ Bm,
    const float* __restrict__ bias, bf16* __restrict__ C,
    int Ndim, int bias_mode)
{
  __shared__ bf16 As[128 * 32];
  __shared__ bf16 Bs[128 * 32];
  const int nbn = Ndim >> 7;
  const int bm = blockIdx.x / nbn, bn = blockIdx.x % nbn;
  const int t = threadIdx.x, w = t >> 6, l = t & 63;
  const int lane16 = l & 15, quad = l >> 4;
  const int wm = (w & 1) << 6, wn = (w >> 1) << 6;
  const int gc = ((t & 3) - (t >> 3)) & 3;
  const bf16* Ag = A + (size_t)(bm << 7) * 256 + (size_t)(t >> 2) * 256 + gc * 8;
  const bf16* Bg = Bm + (size_t)(bn << 7) * 256 + (size_t)(t >> 2) * 256 + gc * 8;
  const int rslot = ((quad + (lane16 >> 1)) & 3) * 8;
  f32x4 acc[4][4] = {};
  for (int kt = 0; kt < 256; kt += 32) {
    __syncthreads();
    g2lds16(As + (w << 9),        Ag + kt);
    g2lds16(As + 2048 + (w << 9), Ag + (size_t)64 * 256 + kt);
    g2lds16(Bs + (w << 9),        Bg + kt);
    g2lds16(Bs + 2048 + (w << 9), Bg + (size_t)64 * 256 + kt);
    __syncthreads();
    bf16x8 af[4], bfr[4];
#pragma unroll
    for (int i = 0; i < 4; ++i)
      af[i] = *(const bf16x8*)(As + (wm + i * 16 + lane16) * 32 + rslot);
#pragma unroll
    for (int i = 0; i < 4; ++i)
      bfr[i] = *(const bf16x8*)(Bs + (wn + i * 16 + lane16) * 32 + rslot);
#pragma unroll
    for (int i = 0; i < 4; ++i)
#pragma unroll
      for (int jx = 0; jx < 4; ++jx)
        acc[i][jx] = MFMA16(af[i], bfr[jx], acc[i][jx]);
  }
#pragma unroll
  for (int i = 0; i < 4; ++i)
#pragma unroll
    for (int jx = 0; jx < 4; ++jx) {
      int col = (bn << 7) + wn + jx * 16 + lane16;
#pragma unroll
      for (int r = 0; r < 4; ++r) {
        int row = (bm << 7) + wm + i * 16 + quad * 4 + r;
        float v = acc[i][jx][r] + (bias_mode ? bias[row] : bias[col]);
        C[(size_t)row * Ndim + col] = (bf16)v;
      }
    }
}

// ---------------- fused attention ----------------
// XCD-swizzled grid: all 32 st-blocks of one (b,n) land on one XCD (2MB K/V slice
// fits its 4MB L2). Block: 4 waves. QK: wave w computes S[16s][32f] (Q in regs).
// P[64s][32f] block-shared (padded rows). PV d-split: wave w computes O[64s][64d].
__global__ __launch_bounds__(256, 4) void attn_k(
    const bf16* __restrict__ X, const bf16* __restrict__ QK, const bf16* __restrict__ Vt,
    const int* __restrict__ mask, const int* __restrict__ flags,
    float* __restrict__ Oacc)
{
  __shared__ bf16 Ks[32 * 256];
  __shared__ bf16 Vs[256 * 32];
  __shared__ bf16 Ps[64 * 40];
  __shared__ float lsumLDS[64];
  // XCD-aware remap: i = xcd + 8*round; round = g_sub*32 + st; group g = xcd + 8*g_sub
  const int i  = blockIdx.x;
  const int x  = i & 7, rr = i >> 3;
  const int g  = x + 8 * (rr >> 5);            // 0..47 = b*12+n
  const int st = rr & 31;
  const int b  = g / 12, n = g % 12;
  const int t = threadIdx.x, w = t >> 6, l = t & 63;
  const int lane16 = l & 15, quad = l >> 4;
  const int sw = (st << 6) + (w << 4);          // wave's 16 QK s-rows (global in batch)
  const bf16* Xb = X + (size_t)b * S_ * D_;
  bf16x8 qf[8];                                  // Q A-frags: 16 rows x 256 k
#pragma unroll
  for (int kt = 0; kt < 8; ++kt)
    qf[kt] = *(const bf16x8*)(Xb + (size_t)(sw + lane16) * D_ + kt * 32 + quad * 8);
  const bf16* QKb = QK + (size_t)b * S_ * J_ + n * D_;
  const bf16* Vtb = Vt + (size_t)n * D_ * M_ + (size_t)b * S_;
  const int* flagb = flags + (b * 32 + st) * 32;
  f32x4 oacc[4][4] = {};                         // O[64s][w*64..w*64+64)
  float lsum[4] = {0.f, 0.f, 0.f, 0.f};

  for (int f0 = 0; f0 < S_; f0 += 32) {
    __syncthreads();                             // prev iter fully consumed Ks/Vs
    // K tile: LDS row=f (512B). Slot chunk l&31 holds global d-chunk (l&31)^(frow&7).
#pragma unroll
    for (int ii = 0; ii < 4; ++ii) {
      int frow = ii * 8 + (t >> 5);
      int dc = (t & 31) ^ (frow & 7);
      g2lds16(Ks + ii * 2048 + (w << 9), QKb + (size_t)(f0 + frow) * J_ + dc * 8);
    }
    // Vt tile: LDS row=d (64B). Slot chunk l&3 holds global f-chunk (l&3)^((drow>>1)&3).
#pragma unroll
    for (int ii = 0; ii < 4; ++ii) {
      int drow = ii * 64 + (t >> 2);
      int fc = (t & 3) ^ ((drow >> 1) & 3);
      g2lds16(Vs + ii * 2048 + (w << 9), Vtb + (size_t)drow * M_ + f0 + fc * 8);
    }
    __syncthreads();                             // staging complete
    // S = Q K^T : 16 x 32
    f32x4 sfr[2] = {};
#pragma unroll
    for (int kt = 0; kt < 8; ++kt)
#pragma unroll
      for (int ct = 0; ct < 2; ++ct) {
        int fl = ct * 16 + lane16;
        bf16x8 kf = *(const bf16x8*)(Ks + fl * 256 + (((kt * 4 + quad) ^ (fl & 7)) * 8));
        sfr[ct] = MFMA16(qf[kt], kf, sfr[ct]);
      }
    // mask + exp (no max-subtraction: |S| <~ 40, fp32 exp safe)
    float ex[2][4];
    if (flagb[f0 >> 6]) {
#pragma unroll
      for (int ct = 0; ct < 2; ++ct)
#pragma unroll
        for (int r = 0; r < 4; ++r) ex[ct][r] = __expf(sfr[ct][r]);
    } else {
#pragma unroll
      for (int ct = 0; ct < 2; ++ct)
#pragma unroll
        for (int r = 0; r < 4; ++r) {
          int s = sw + quad * 4 + r, f = f0 + ct * 16 + lane16;
          float add = (1.0f - (float)mask[(size_t)b * S_ * S_ + (size_t)s * S_ + f]) * -10000.0f;
          ex[ct][r] = __expf(sfr[ct][r] + add);
        }
    }
    // row sums (row s=quad*4+r lives across the quad's 16 contiguous lanes)
#pragma unroll
    for (int r = 0; r < 4; ++r) {
      float rs = ex[0][r] + ex[1][r];
      rs += __shfl_xor(rs, 1, 16);
      rs += __shfl_xor(rs, 2, 16);
      rs += __shfl_xor(rs, 4, 16);
      rs += __shfl_xor(rs, 8, 16);
      lsum[r] += rs;
    }
    // P -> shared LDS [64s][40] (wave w owns rows w*16..w*16+15)
#pragma unroll
    for (int ct = 0; ct < 2; ++ct)
#pragma unroll
      for (int r = 0; r < 4; ++r) {
        int srow = (w << 4) + quad * 4 + r, f = ct * 16 + lane16;
        Ps[srow * 40 + f] = (bf16)ex[ct][r];
      }
    __syncthreads();                             // all P visible
    // O[64s][64d-slice] += P * V  (A = P[s][f], B = Vt[d][f]); wave w: d in [w*64, w*64+64)
#pragma unroll
    for (int dt = 0; dt < 4; ++dt) {
      int dl = (w << 6) + dt * 16 + lane16;
      bf16x8 vf = *(const bf16x8*)(Vs + dl * 32 + ((quad ^ ((dl >> 1) & 3)) * 8));
#pragma unroll
      for (int ts = 0; ts < 4; ++ts) {
        bf16x8 pf = *(const bf16x8*)(&Ps[(ts * 16 + lane16) * 40 + quad * 8]);
        oacc[ts][dt] = MFMA16(pf, vf, oacc[ts][dt]);
      }
    }
  }
  // share row sums (wave w owns rows w*16..): lane16==0 lanes write 4 rows each
  if (lane16 == 0) {
#pragma unroll
    for (int r = 0; r < 4; ++r)
      lsumLDS[(w << 4) + quad * 4 + r] = lsum[r];
  }
  __syncthreads();
  // normalize and head-sum into fp32 output: wave w writes all 64 s, its 64 d
  float* Ob = Oacc + (size_t)b * S_ * D_;
#pragma unroll
  for (int ts = 0; ts < 4; ++ts) {
#pragma unroll
    for (int r = 0; r < 4; ++r) {
      int sl = ts * 16 + quad * 4 + r;
      float inv = 1.0f / lsumLDS[sl];
      int s = (st << 6) + sl;
#pragma unroll
      for (int dt = 0; dt < 4; ++dt) {
        int d = (w << 6) + dt * 16 + lane16;
        unsafeAtomicAdd(&Ob[(size_t)s * D_ + d], oacc[ts][dt][r] * inv);
      }
    }
  }
}

extern "C" void kernel_launch(void* const* d_in, const int* in_sizes, int n_in,
                              void* d_out, int out_size, void* d_ws, size_t ws_size,
                              hipStream_t stream) {
  (void)in_sizes; (void)n_in; (void)out_size; (void)ws_size;
  const float* X    = (const float*)d_in[0];   // fp32 per reference
  const int*   mask = (const int*)d_in[1];
  const float* Wqk  = (const float*)d_in[2];
  const float* bqk  = (const float*)d_in[3];
  const float* Wv   = (const float*)d_in[4];
  const float* bv   = (const float*)d_in[5];
  float* out = (float*)d_out;                  // fp32 per reference output

  char* p = (char*)d_ws;
  bf16*  Xbf  = (bf16*)p;  p += (size_t)M_ * D_ * 2;      // 4.2 MB
  bf16*  Wqkt = (bf16*)p;  p += (size_t)J_ * D_ * 2;      // 1.5 MB
  bf16*  Wvt  = (bf16*)p;  p += (size_t)J_ * D_ * 2;      // 1.5 MB
  bf16*  QKw  = (bf16*)p;  p += (size_t)M_ * J_ * 2;      // 50.3 MB  [m][j]
  bf16*  Vtw  = (bf16*)p;  p += (size_t)J_ * M_ * 2;      // 50.3 MB  [j][m]
  int*   flags= (int*)p;   p += 4096 * 4;

  hipMemsetAsync(out, 0, (size_t)M_ * D_ * 4, stream);    // we accumulate into out
  cvt_x<<<(M_ * D_) / (256 * 4), 256, 0, stream>>>(X, Xbf);
  transpose_w<<<dim3(12, 16), 256, 0, stream>>>(Wqk, Wqkt);
  transpose_w<<<dim3(12, 16), 256, 0, stream>>>(Wv, Wvt);
  mask_flags_k<<<4096, 256, 0, stream>>>(mask, flags);
  gemm_bt<<<(M_ / 128) * (J_ / 128), 256, 0, stream>>>(Xbf, Wqkt, bqk, QKw, J_, 0);
  gemm_bt<<<(J_ / 128) * (M_ / 128), 256, 0, stream>>>(Wvt, Xbf, bv, Vtw, M_, 1);
  attn_k<<<B_ * NH_ * (S_ / 64), 256, 0, stream>>>(Xbf, QKw, Vtw, mask, flags, out);
}

// Round 6
// 507.934 us; speedup vs baseline: 1.5209x; 1.1819x over previous
//
#include <hip/hip_runtime.h>
#include <stdint.h>

#define B_ 4
#define S_ 2048
#define D_ 256
#define NH_ 12
#define M_ (B_*S_)      // 8192 rows of flattened input
#define J_ (NH_*D_)     // 3072 projection cols

typedef __bf16 bf16;
typedef __bf16 bf16x8 __attribute__((ext_vector_type(8)));
typedef __bf16 bf16x4 __attribute__((ext_vector_type(4)));
typedef float  f32x4  __attribute__((ext_vector_type(4)));

#define MFMA16(a,b,c) __builtin_amdgcn_mfma_f32_16x16x32_bf16(a,b,c,0,0,0)

__device__ __forceinline__ void g2lds16(void* l, const void* g) {
  __builtin_amdgcn_global_load_lds(
      (const __attribute__((address_space(1))) unsigned int*)g,
      (__attribute__((address_space(3))) unsigned int*)l, 16, 0, 0);
}

// ---------------- X fp32 -> bf16 ----------------
__global__ __launch_bounds__(256) void cvt_x(const float* __restrict__ in,
                                             bf16* __restrict__ out) {
  int i = blockIdx.x * 256 + threadIdx.x;
  f32x4 v = *(const f32x4*)(in + (size_t)i * 4);
  bf16x4 o;
#pragma unroll
  for (int k = 0; k < 4; ++k) o[k] = (bf16)v[k];
  *(bf16x4*)(out + (size_t)i * 4) = o;
}

// ---------------- weight transpose+cvt: W fp32 [256][3072] -> Wt bf16 [3072][256] ----------------
__global__ __launch_bounds__(256) void transpose_w(const float* __restrict__ W,
                                                   bf16* __restrict__ Wt) {
  int j  = blockIdx.x * 256 + threadIdx.x;   // 0..3071, coalesced reads over j
  int c0 = blockIdx.y * 16;
  bf16x8 v0, v1;
#pragma unroll
  for (int i = 0; i < 8; ++i) v0[i] = (bf16)W[(size_t)(c0 + i) * J_ + j];
#pragma unroll
  for (int i = 0; i < 8; ++i) v1[i] = (bf16)W[(size_t)(c0 + 8 + i) * J_ + j];
  *(bf16x8*)(Wt + (size_t)j * D_ + c0)     = v0;
  *(bf16x8*)(Wt + (size_t)j * D_ + c0 + 8) = v1;
}

// ---------------- mask tile flags: 1 if 64x64 tile is all ones ----------------
__global__ __launch_bounds__(256) void mask_flags_k(const int* __restrict__ mask,
                                                    int* __restrict__ flags) {
  int bx = blockIdx.x;                 // b*1024 + st*32 + ft
  int ft = bx & 31, st = (bx >> 5) & 31, b = bx >> 10;
  int t = threadIdx.x;
  const int4* mp4 = (const int4*)(mask + (size_t)b * S_ * S_ +
                                  (size_t)(st * 64 + (t >> 2)) * S_ + ft * 64 + (t & 3) * 16);
  bool ok = true;
#pragma unroll
  for (int i = 0; i < 4; ++i) {
    int4 v = mp4[i];
    ok &= (v.x == 1) & (v.y == 1) & (v.z == 1) & (v.w == 1);
  }
  __shared__ int flag;
  if (t == 0) flag = 1;
  __syncthreads();
  if (!ok) flag = 0;                   // benign race, all write 0
  __syncthreads();
  if (t == 0) flags[bx] = flag;
}

// ---------------- GEMM: C[M][N] = A[M][256] * Bm[N][256]^T + bias ----------------
// 128x128 tile, BK=32, 4 waves each 64x64. XOR k-chunk swizzle -> 2-way banks (free).
__global__ __launch_bounds__(256) void gemm_bt(
    const bf16* __restrict__ A, const bf16* __restrict__ Bm,
    const float* __restrict__ bias, bf16* __restrict__ C,
    int Ndim, int bias_mode)
{
  __shared__ bf16 As[128 * 32];
  __shared__ bf16 Bs[128 * 32];
  const int nbn = Ndim >> 7;
  const int bm = blockIdx.x / nbn, bn = blockIdx.x % nbn;
  const int t = threadIdx.x, w = t >> 6, l = t & 63;
  const int lane16 = l & 15, quad = l >> 4;
  const int wm = (w & 1) << 6, wn = (w >> 1) << 6;
  const int gc = ((t & 3) - (t >> 3)) & 3;
  const bf16* Ag = A + (size_t)(bm << 7) * 256 + (size_t)(t >> 2) * 256 + gc * 8;
  const bf16* Bg = Bm + (size_t)(bn << 7) * 256 + (size_t)(t >> 2) * 256 + gc * 8;
  const int rslot = ((quad + (lane16 >> 1)) & 3) * 8;
  f32x4 acc[4][4] = {};
  for (int kt = 0; kt < 256; kt += 32) {
    __syncthreads();
    g2lds16(As + (w << 9),        Ag + kt);
    g2lds16(As + 2048 + (w << 9), Ag + (size_t)64 * 256 + kt);
    g2lds16(Bs + (w << 9),        Bg + kt);
    g2lds16(Bs + 2048 + (w << 9), Bg + (size_t)64 * 256 + kt);
    __syncthreads();
    bf16x8 af[4], bfr[4];
#pragma unroll
    for (int i = 0; i < 4; ++i)
      af[i] = *(const bf16x8*)(As + (wm + i * 16 + lane16) * 32 + rslot);
#pragma unroll
    for (int i = 0; i < 4; ++i)
      bfr[i] = *(const bf16x8*)(Bs + (wn + i * 16 + lane16) * 32 + rslot);
#pragma unroll
    for (int i = 0; i < 4; ++i)
#pragma unroll
      for (int jx = 0; jx < 4; ++jx)
        acc[i][jx] = MFMA16(af[i], bfr[jx], acc[i][jx]);
  }
#pragma unroll
  for (int i = 0; i < 4; ++i)
#pragma unroll
    for (int jx = 0; jx < 4; ++jx) {
      int col = (bn << 7) + wn + jx * 16 + lane16;
#pragma unroll
      for (int r = 0; r < 4; ++r) {
        int row = (bm << 7) + wm + i * 16 + quad * 4 + r;
        float v = acc[i][jx][r] + (bias_mode ? bias[row] : bias[col]);
        C[(size_t)row * Ndim + col] = (bf16)v;
      }
    }
}

// ---------------- fused attention ----------------
// XCD-swizzled grid, 16 st-blocks per (b,n) on one XCD. Block: 4 waves, 128 s-rows.
// Wave w: QK for s-rows w*32..w*32+31 (TWO 16-row s-tiles, Q in regs) -> each kf read
// feeds 2 MFMAs. P[128s][40] block-shared. PV d-split: wave w -> O[128s][64d],
// vf hoisted (4 reads) + pf (8 reads) per iter.
__global__ __launch_bounds__(256, 2) void attn_k(
    const bf16* __restrict__ X, const bf16* __restrict__ QK, const bf16* __restrict__ Vt,
    const int* __restrict__ mask, const int* __restrict__ flags,
    float* __restrict__ Oacc)
{
  __shared__ bf16 Ks[32 * 256];
  __shared__ bf16 Vs[256 * 32];
  __shared__ bf16 Ps[128 * 40];
  __shared__ float lsumLDS[128];
  // XCD-aware remap: i = xcd + 8*round; round = g_sub*16 + st; group g = xcd + 8*g_sub
  const int i  = blockIdx.x;
  const int x  = i & 7, rr = i >> 3;
  const int g  = x + 8 * (rr >> 4);            // 0..47 = b*12+n
  const int st = rr & 15;                      // 128-row s-tile
  const int b  = g / 12, n = g % 12;
  const int t = threadIdx.x, w = t >> 6, l = t & 63;
  const int lane16 = l & 15, quad = l >> 4;
  const int sw = (st << 7) + (w << 5);          // wave's first of 32 QK s-rows
  const bf16* Xb = X + (size_t)b * S_ * D_;
  bf16x8 qf[2][8];                              // Q A-frags: 2 s-tiles x 256 k
#pragma unroll
  for (int ts = 0; ts < 2; ++ts)
#pragma unroll
    for (int kt = 0; kt < 8; ++kt)
      qf[ts][kt] = *(const bf16x8*)(Xb + (size_t)(sw + ts * 16 + lane16) * D_ + kt * 32 + quad * 8);
  const bf16* QKb = QK + (size_t)b * S_ * J_ + n * D_;
  const bf16* Vtb = Vt + (size_t)n * D_ * M_ + (size_t)b * S_;
  // flags row for this wave's 64-row tile: st*2 + (w>>1)
  const int* flagb = flags + (b * 32 + st * 2 + (w >> 1)) * 32;
  f32x4 oacc[8][4] = {};                        // O[128s][w*64 + 64d)
  float lsum[2][4] = {};                        // per-lane partial row sums

  for (int f0 = 0; f0 < S_; f0 += 32) {
    __syncthreads();                             // prev iter fully consumed Ks/Vs/Ps
    // K tile: LDS row=f (512B). Slot chunk l&31 holds global d-chunk (l&31)^(frow&7).
#pragma unroll
    for (int ii = 0; ii < 4; ++ii) {
      int frow = ii * 8 + (t >> 5);
      int dc = (t & 31) ^ (frow & 7);
      g2lds16(Ks + ii * 2048 + (w << 9), QKb + (size_t)(f0 + frow) * J_ + dc * 8);
    }
    // Vt tile: LDS row=d (64B). Slot chunk l&3 holds global f-chunk (l&3)^((drow>>1)&3).
#pragma unroll
    for (int ii = 0; ii < 4; ++ii) {
      int drow = ii * 64 + (t >> 2);
      int fc = (t & 3) ^ ((drow >> 1) & 3);
      g2lds16(Vs + ii * 2048 + (w << 9), Vtb + (size_t)drow * M_ + f0 + fc * 8);
    }
    __syncthreads();                             // staging complete
    // S = Q K^T : 32s x 32f (2 s-tiles share each kf read)
    f32x4 sfr[2][2] = {};
#pragma unroll
    for (int kt = 0; kt < 8; ++kt)
#pragma unroll
      for (int ct = 0; ct < 2; ++ct) {
        int fl = ct * 16 + lane16;
        bf16x8 kf = *(const bf16x8*)(Ks + fl * 256 + (((kt * 4 + quad) ^ (fl & 7)) * 8));
        sfr[0][ct] = MFMA16(qf[0][kt], kf, sfr[0][ct]);
        sfr[1][ct] = MFMA16(qf[1][kt], kf, sfr[1][ct]);
      }
    // mask + exp (no max-subtraction: |S| <~ 40, fp32 exp safe)
    float ex[2][2][4];
    if (flagb[f0 >> 6]) {
#pragma unroll
      for (int ts = 0; ts < 2; ++ts)
#pragma unroll
        for (int ct = 0; ct < 2; ++ct)
#pragma unroll
          for (int r = 0; r < 4; ++r) ex[ts][ct][r] = __expf(sfr[ts][ct][r]);
    } else {
#pragma unroll
      for (int ts = 0; ts < 2; ++ts)
#pragma unroll
        for (int ct = 0; ct < 2; ++ct)
#pragma unroll
          for (int r = 0; r < 4; ++r) {
            int s = sw + ts * 16 + quad * 4 + r, f = f0 + ct * 16 + lane16;
            float add = (1.0f - (float)mask[(size_t)b * S_ * S_ + (size_t)s * S_ + f]) * -10000.0f;
            ex[ts][ct][r] = __expf(sfr[ts][ct][r] + add);
          }
    }
    // per-lane partial row sums (cross-lane reduce deferred to end of kernel)
#pragma unroll
    for (int ts = 0; ts < 2; ++ts)
#pragma unroll
      for (int r = 0; r < 4; ++r)
        lsum[ts][r] += ex[ts][0][r] + ex[ts][1][r];
    // P -> shared LDS [128s][40] (wave w owns rows w*32..w*32+31)
#pragma unroll
    for (int ts = 0; ts < 2; ++ts)
#pragma unroll
      for (int ct = 0; ct < 2; ++ct)
#pragma unroll
        for (int r = 0; r < 4; ++r) {
          int srow = (w << 5) + ts * 16 + quad * 4 + r, f = ct * 16 + lane16;
          Ps[srow * 40 + f] = (bf16)ex[ts][ct][r];
        }
    __syncthreads();                             // all P visible
    // O[128s][64d-slice] += P * V; vf hoisted, pf once per s-tile
    bf16x8 vf[4];
#pragma unroll
    for (int dt = 0; dt < 4; ++dt) {
      int dl = (w << 6) + dt * 16 + lane16;
      vf[dt] = *(const bf16x8*)(Vs + dl * 32 + ((quad ^ ((dl >> 1) & 3)) * 8));
    }
#pragma unroll
    for (int ts8 = 0; ts8 < 8; ++ts8) {
      bf16x8 pf = *(const bf16x8*)(&Ps[(ts8 * 16 + lane16) * 40 + quad * 8]);
#pragma unroll
      for (int dt = 0; dt < 4; ++dt)
        oacc[ts8][dt] = MFMA16(pf, vf[dt], oacc[ts8][dt]);
    }
  }
  // finalize row sums: reduce across the quad's 16 lanes, share via LDS
#pragma unroll
  for (int ts = 0; ts < 2; ++ts)
#pragma unroll
    for (int r = 0; r < 4; ++r) {
      float rs = lsum[ts][r];
      rs += __shfl_xor(rs, 1, 16);
      rs += __shfl_xor(rs, 2, 16);
      rs += __shfl_xor(rs, 4, 16);
      rs += __shfl_xor(rs, 8, 16);
      if (lane16 == 0) lsumLDS[(w << 5) + ts * 16 + quad * 4 + r] = rs;
    }
  __syncthreads();
  // normalize and head-sum into fp32 output: wave w writes all 128 s, its 64 d
  float* Ob = Oacc + (size_t)b * S_ * D_;
#pragma unroll
  for (int ts8 = 0; ts8 < 8; ++ts8) {
#pragma unroll
    for (int r = 0; r < 4; ++r) {
      int sl = ts8 * 16 + quad * 4 + r;
      float inv = 1.0f / lsumLDS[sl];
      int s = (st << 7) + sl;
#pragma unroll
      for (int dt = 0; dt < 4; ++dt) {
        int d = (w << 6) + dt * 16 + lane16;
        unsafeAtomicAdd(&Ob[(size_t)s * D_ + d], oacc[ts8][dt][r] * inv);
      }
    }
  }
}

extern "C" void kernel_launch(void* const* d_in, const int* in_sizes, int n_in,
                              void* d_out, int out_size, void* d_ws, size_t ws_size,
                              hipStream_t stream) {
  (void)in_sizes; (void)n_in; (void)out_size; (void)ws_size;
  const float* X    = (const float*)d_in[0];   // fp32 per reference
  const int*   mask = (const int*)d_in[1];
  const float* Wqk  = (const float*)d_in[2];
  const float* bqk  = (const float*)d_in[3];
  const float* Wv   = (const float*)d_in[4];
  const float* bv   = (const float*)d_in[5];
  float* out = (float*)d_out;                  // fp32 per reference output

  char* p = (char*)d_ws;
  bf16*  Xbf  = (bf16*)p;  p += (size_t)M_ * D_ * 2;      // 4.2 MB
  bf16*  Wqkt = (bf16*)p;  p += (size_t)J_ * D_ * 2;      // 1.5 MB
  bf16*  Wvt  = (bf16*)p;  p += (size_t)J_ * D_ * 2;      // 1.5 MB
  bf16*  QKw  = (bf16*)p;  p += (size_t)M_ * J_ * 2;      // 50.3 MB  [m][j]
  bf16*  Vtw  = (bf16*)p;  p += (size_t)J_ * M_ * 2;      // 50.3 MB  [j][m]
  int*   flags= (int*)p;   p += 4096 * 4;

  hipMemsetAsync(out, 0, (size_t)M_ * D_ * 4, stream);    // we accumulate into out
  cvt_x<<<(M_ * D_) / (256 * 4), 256, 0, stream>>>(X, Xbf);
  transpose_w<<<dim3(12, 16), 256, 0, stream>>>(Wqk, Wqkt);
  transpose_w<<<dim3(12, 16), 256, 0, stream>>>(Wv, Wvt);
  mask_flags_k<<<4096, 256, 0, stream>>>(mask, flags);
  gemm_bt<<<(M_ / 128) * (J_ / 128), 256, 0, stream>>>(Xbf, Wqkt, bqk, QKw, J_, 0);
  gemm_bt<<<(J_ / 128) * (M_ / 128), 256, 0, stream>>>(Wvt, Xbf, bv, Vtw, M_, 1);
  attn_k<<<B_ * NH_ * (S_ / 128), 256, 0, stream>>>(Xbf, QKw, Vtw, mask, flags, out);
}

// Round 7
// 505.896 us; speedup vs baseline: 1.5270x; 1.0040x over previous
//
#include <hip/hip_runtime.h>
#include <stdint.h>

#define B_ 4
#define S_ 2048
#define D_ 256
#define NH_ 12
#define M_ (B_*S_)      // 8192 rows of flattened input
#define J_ (NH_*D_)     // 3072 projection cols

typedef __bf16 bf16;
typedef __bf16 bf16x8 __attribute__((ext_vector_type(8)));
typedef __bf16 bf16x4 __attribute__((ext_vector_type(4)));
typedef float  f32x4  __attribute__((ext_vector_type(4)));

#define MFMA16(a,b,c) __builtin_amdgcn_mfma_f32_16x16x32_bf16(a,b,c,0,0,0)

__device__ __forceinline__ void g2lds16(void* l, const void* g) {
  __builtin_amdgcn_global_load_lds(
      (const __attribute__((address_space(1))) unsigned int*)g,
      (__attribute__((address_space(3))) unsigned int*)l, 16, 0, 0);
}

// ---------------- X fp32 -> bf16 ----------------
__global__ __launch_bounds__(256) void cvt_x(const float* __restrict__ in,
                                             bf16* __restrict__ out) {
  int i = blockIdx.x * 256 + threadIdx.x;
  f32x4 v = *(const f32x4*)(in + (size_t)i * 4);
  bf16x4 o;
#pragma unroll
  for (int k = 0; k < 4; ++k) o[k] = (bf16)v[k];
  *(bf16x4*)(out + (size_t)i * 4) = o;
}

// ---------------- weight transpose+cvt: W fp32 [256][3072] -> Wt bf16 [3072][256] ----------------
__global__ __launch_bounds__(256) void transpose_w(const float* __restrict__ W,
                                                   bf16* __restrict__ Wt) {
  int j  = blockIdx.x * 256 + threadIdx.x;   // 0..3071, coalesced reads over j
  int c0 = blockIdx.y * 16;
  bf16x8 v0, v1;
#pragma unroll
  for (int i = 0; i < 8; ++i) v0[i] = (bf16)W[(size_t)(c0 + i) * J_ + j];
#pragma unroll
  for (int i = 0; i < 8; ++i) v1[i] = (bf16)W[(size_t)(c0 + 8 + i) * J_ + j];
  *(bf16x8*)(Wt + (size_t)j * D_ + c0)     = v0;
  *(bf16x8*)(Wt + (size_t)j * D_ + c0 + 8) = v1;
}

// ---------------- mask tile flags: 1 if 64x64 tile is all ones ----------------
__global__ __launch_bounds__(256) void mask_flags_k(const int* __restrict__ mask,
                                                    int* __restrict__ flags) {
  int bx = blockIdx.x;                 // b*1024 + st*32 + ft
  int ft = bx & 31, st = (bx >> 5) & 31, b = bx >> 10;
  int t = threadIdx.x;
  const int4* mp4 = (const int4*)(mask + (size_t)b * S_ * S_ +
                                  (size_t)(st * 64 + (t >> 2)) * S_ + ft * 64 + (t & 3) * 16);
  bool ok = true;
#pragma unroll
  for (int i = 0; i < 4; ++i) {
    int4 v = mp4[i];
    ok &= (v.x == 1) & (v.y == 1) & (v.z == 1) & (v.w == 1);
  }
  __shared__ int flag;
  if (t == 0) flag = 1;
  __syncthreads();
  if (!ok) flag = 0;                   // benign race, all write 0
  __syncthreads();
  if (t == 0) flags[bx] = flag;
}

// ---------------- GEMM: C[M][N] = A[M][256] * Bm[N][256]^T + bias ----------------
// 128x128 tile, BK=32, 4 waves each 64x64. XOR k-chunk swizzle -> 2-way banks (free).
__global__ __launch_bounds__(256) void gemm_bt(
    const bf16* __restrict__ A, const bf16* __restrict__ Bm,
    const float* __restrict__ bias, bf16* __restrict__ C,
    int Ndim, int bias_mode)
{
  __shared__ bf16 As[128 * 32];
  __shared__ bf16 Bs[128 * 32];
  const int nbn = Ndim >> 7;
  const int bm = blockIdx.x / nbn, bn = blockIdx.x % nbn;
  const int t = threadIdx.x, w = t >> 6, l = t & 63;
  const int lane16 = l & 15, quad = l >> 4;
  const int wm = (w & 1) << 6, wn = (w >> 1) << 6;
  const int gc = ((t & 3) - (t >> 3)) & 3;
  const bf16* Ag = A + (size_t)(bm << 7) * 256 + (size_t)(t >> 2) * 256 + gc * 8;
  const bf16* Bg = Bm + (size_t)(bn << 7) * 256 + (size_t)(t >> 2) * 256 + gc * 8;
  const int rslot = ((quad + (lane16 >> 1)) & 3) * 8;
  f32x4 acc[4][4] = {};
  for (int kt = 0; kt < 256; kt += 32) {
    __syncthreads();
    g2lds16(As + (w << 9),        Ag + kt);
    g2lds16(As + 2048 + (w << 9), Ag + (size_t)64 * 256 + kt);
    g2lds16(Bs + (w << 9),        Bg + kt);
    g2lds16(Bs + 2048 + (w << 9), Bg + (size_t)64 * 256 + kt);
    __syncthreads();
    bf16x8 af[4], bfr[4];
#pragma unroll
    for (int i = 0; i < 4; ++i)
      af[i] = *(const bf16x8*)(As + (wm + i * 16 + lane16) * 32 + rslot);
#pragma unroll
    for (int i = 0; i < 4; ++i)
      bfr[i] = *(const bf16x8*)(Bs + (wn + i * 16 + lane16) * 32 + rslot);
#pragma unroll
    for (int i = 0; i < 4; ++i)
#pragma unroll
      for (int jx = 0; jx < 4; ++jx)
        acc[i][jx] = MFMA16(af[i], bfr[jx], acc[i][jx]);
  }
#pragma unroll
  for (int i = 0; i < 4; ++i)
#pragma unroll
    for (int jx = 0; jx < 4; ++jx) {
      int col = (bn << 7) + wn + jx * 16 + lane16;
#pragma unroll
      for (int r = 0; r < 4; ++r) {
        int row = (bm << 7) + wm + i * 16 + quad * 4 + r;
        float v = acc[i][jx][r] + (bias_mode ? bias[row] : bias[col]);
        C[(size_t)row * Ndim + col] = (bf16)v;
      }
    }
}

// ---------------- fused attention ----------------
// XCD-swizzled grid. Block: 4 waves, 128 s-rows. K/V DOUBLE-BUFFERED with
// one-iteration prefetch: top barrier drains DMA issued a full iter earlier
// (free), P-barrier drains prefetch that has had the QK phase to land (cheap).
// 2 barriers/iter (was 3, with exposed staging latency).
__global__ __launch_bounds__(256, 2) void attn_k(
    const bf16* __restrict__ X, const bf16* __restrict__ QK, const bf16* __restrict__ Vt,
    const int* __restrict__ mask, const int* __restrict__ flags,
    float* __restrict__ Oacc)
{
  __shared__ bf16 Ks[2][32 * 256];
  __shared__ bf16 Vs[2][256 * 32];
  __shared__ bf16 Ps[128 * 40];
  __shared__ float lsumLDS[128];
  // XCD-aware remap: i = xcd + 8*round; round = g_sub*16 + st; group g = xcd + 8*g_sub
  const int i  = blockIdx.x;
  const int x  = i & 7, rr = i >> 3;
  const int g  = x + 8 * (rr >> 4);            // 0..47 = b*12+n
  const int st = rr & 15;                      // 128-row s-tile
  const int b  = g / 12, n = g % 12;
  const int t = threadIdx.x, w = t >> 6, l = t & 63;
  const int lane16 = l & 15, quad = l >> 4;
  const int sw = (st << 7) + (w << 5);          // wave's first of 32 QK s-rows
  const bf16* Xb = X + (size_t)b * S_ * D_;
  bf16x8 qf[2][8];                              // Q A-frags: 2 s-tiles x 256 k
#pragma unroll
  for (int ts = 0; ts < 2; ++ts)
#pragma unroll
    for (int kt = 0; kt < 8; ++kt)
      qf[ts][kt] = *(const bf16x8*)(Xb + (size_t)(sw + ts * 16 + lane16) * D_ + kt * 32 + quad * 8);
  const bf16* QKb = QK + (size_t)b * S_ * J_ + n * D_;
  const bf16* Vtb = Vt + (size_t)n * D_ * M_ + (size_t)b * S_;
  // flags row for this wave's 64-row tile: st*2 + (w>>1)
  const int* flagb = flags + (b * 32 + st * 2 + (w >> 1)) * 32;
  f32x4 oacc[8][4] = {};                        // O[128s][w*64 + 64d)
  float lsum[2][4] = {};                        // per-lane partial row sums

  // staging helper: loads f-tile f0 into buffer `buf`
  auto stage = [&](int buf, int f0) {
    // K tile: LDS row=f (512B). Slot chunk l&31 holds global d-chunk (l&31)^(frow&7).
#pragma unroll
    for (int ii = 0; ii < 4; ++ii) {
      int frow = ii * 8 + (t >> 5);
      int dc = (t & 31) ^ (frow & 7);
      g2lds16(&Ks[buf][ii * 2048 + (w << 9)], QKb + (size_t)(f0 + frow) * J_ + dc * 8);
    }
    // Vt tile: LDS row=d (64B). Slot chunk l&3 holds global f-chunk (l&3)^((drow>>1)&3).
#pragma unroll
    for (int ii = 0; ii < 4; ++ii) {
      int drow = ii * 64 + (t >> 2);
      int fc = (t & 3) ^ ((drow >> 1) & 3);
      g2lds16(&Vs[buf][ii * 2048 + (w << 9)], Vtb + (size_t)drow * M_ + f0 + fc * 8);
    }
  };

  stage(0, 0);                                  // prologue prefetch
  int cur = 0;
  for (int f0 = 0; f0 < S_; f0 += 32) {
    __syncthreads();       // DMA(cur) complete (issued a full iter ago); buf cur^1 free
    if (f0 + 32 < S_) stage(cur ^ 1, f0 + 32);  // prefetch next tile (covered by compute)
    // S = Q K^T : 32s x 32f (2 s-tiles share each kf read)
    f32x4 sfr[2][2] = {};
#pragma unroll
    for (int kt = 0; kt < 8; ++kt)
#pragma unroll
      for (int ct = 0; ct < 2; ++ct) {
        int fl = ct * 16 + lane16;
        bf16x8 kf = *(const bf16x8*)(&Ks[cur][fl * 256 + (((kt * 4 + quad) ^ (fl & 7)) * 8)]);
        sfr[0][ct] = MFMA16(qf[0][kt], kf, sfr[0][ct]);
        sfr[1][ct] = MFMA16(qf[1][kt], kf, sfr[1][ct]);
      }
    // mask + exp (no max-subtraction: |S| <~ 40, fp32 exp safe)
    float ex[2][2][4];
    if (flagb[f0 >> 6]) {
#pragma unroll
      for (int ts = 0; ts < 2; ++ts)
#pragma unroll
        for (int ct = 0; ct < 2; ++ct)
#pragma unroll
          for (int r = 0; r < 4; ++r) ex[ts][ct][r] = __expf(sfr[ts][ct][r]);
    } else {
#pragma unroll
      for (int ts = 0; ts < 2; ++ts)
#pragma unroll
        for (int ct = 0; ct < 2; ++ct)
#pragma unroll
          for (int r = 0; r < 4; ++r) {
            int s = sw + ts * 16 + quad * 4 + r, f = f0 + ct * 16 + lane16;
            float add = (1.0f - (float)mask[(size_t)b * S_ * S_ + (size_t)s * S_ + f]) * -10000.0f;
            ex[ts][ct][r] = __expf(sfr[ts][ct][r] + add);
          }
    }
    // per-lane partial row sums (cross-lane reduce deferred to end of kernel)
#pragma unroll
    for (int ts = 0; ts < 2; ++ts)
#pragma unroll
      for (int r = 0; r < 4; ++r)
        lsum[ts][r] += ex[ts][0][r] + ex[ts][1][r];
    // P -> shared LDS [128s][40] (wave w owns rows w*32..w*32+31)
#pragma unroll
    for (int ts = 0; ts < 2; ++ts)
#pragma unroll
      for (int ct = 0; ct < 2; ++ct)
#pragma unroll
        for (int r = 0; r < 4; ++r) {
          int srow = (w << 5) + ts * 16 + quad * 4 + r, f = ct * 16 + lane16;
          Ps[srow * 40 + f] = (bf16)ex[ts][ct][r];
        }
    __syncthreads();       // P visible; prefetch DMA has had the QK phase to land
    // O[128s][64d-slice] += P * V; vf hoisted, pf once per s-tile
    bf16x8 vf[4];
#pragma unroll
    for (int dt = 0; dt < 4; ++dt) {
      int dl = (w << 6) + dt * 16 + lane16;
      vf[dt] = *(const bf16x8*)(&Vs[cur][dl * 32 + ((quad ^ ((dl >> 1) & 3)) * 8)]);
    }
#pragma unroll
    for (int ts8 = 0; ts8 < 8; ++ts8) {
      bf16x8 pf = *(const bf16x8*)(&Ps[(ts8 * 16 + lane16) * 40 + quad * 8]);
#pragma unroll
      for (int dt = 0; dt < 4; ++dt)
        oacc[ts8][dt] = MFMA16(pf, vf[dt], oacc[ts8][dt]);
    }
    cur ^= 1;
  }
  // finalize row sums: reduce across the quad's 16 lanes, share via LDS
#pragma unroll
  for (int ts = 0; ts < 2; ++ts)
#pragma unroll
    for (int r = 0; r < 4; ++r) {
      float rs = lsum[ts][r];
      rs += __shfl_xor(rs, 1, 16);
      rs += __shfl_xor(rs, 2, 16);
      rs += __shfl_xor(rs, 4, 16);
      rs += __shfl_xor(rs, 8, 16);
      if (lane16 == 0) lsumLDS[(w << 5) + ts * 16 + quad * 4 + r] = rs;
    }
  __syncthreads();
  // normalize and head-sum into fp32 output: wave w writes all 128 s, its 64 d
  float* Ob = Oacc + (size_t)b * S_ * D_;
#pragma unroll
  for (int ts8 = 0; ts8 < 8; ++ts8) {
#pragma unroll
    for (int r = 0; r < 4; ++r) {
      int sl = ts8 * 16 + quad * 4 + r;
      float inv = 1.0f / lsumLDS[sl];
      int s = (st << 7) + sl;
#pragma unroll
      for (int dt = 0; dt < 4; ++dt) {
        int d = (w << 6) + dt * 16 + lane16;
        unsafeAtomicAdd(&Ob[(size_t)s * D_ + d], oacc[ts8][dt][r] * inv);
      }
    }
  }
}

extern "C" void kernel_launch(void* const* d_in, const int* in_sizes, int n_in,
                              void* d_out, int out_size, void* d_ws, size_t ws_size,
                              hipStream_t stream) {
  (void)in_sizes; (void)n_in; (void)out_size; (void)ws_size;
  const float* X    = (const float*)d_in[0];   // fp32 per reference
  const int*   mask = (const int*)d_in[1];
  const float* Wqk  = (const float*)d_in[2];
  const float* bqk  = (const float*)d_in[3];
  const float* Wv   = (const float*)d_in[4];
  const float* bv   = (const float*)d_in[5];
  float* out = (float*)d_out;                  // fp32 per reference output

  char* p = (char*)d_ws;
  bf16*  Xbf  = (bf16*)p;  p += (size_t)M_ * D_ * 2;      // 4.2 MB
  bf16*  Wqkt = (bf16*)p;  p += (size_t)J_ * D_ * 2;      // 1.5 MB
  bf16*  Wvt  = (bf16*)p;  p += (size_t)J_ * D_ * 2;      // 1.5 MB
  bf16*  QKw  = (bf16*)p;  p += (size_t)M_ * J_ * 2;      // 50.3 MB  [m][j]
  bf16*  Vtw  = (bf16*)p;  p += (size_t)J_ * M_ * 2;      // 50.3 MB  [j][m]
  int*   flags= (int*)p;   p += 4096 * 4;

  hipMemsetAsync(out, 0, (size_t)M_ * D_ * 4, stream);    // we accumulate into out
  cvt_x<<<(M_ * D_) / (256 * 4), 256, 0, stream>>>(X, Xbf);
  transpose_w<<<dim3(12, 16), 256, 0, stream>>>(Wqk, Wqkt);
  transpose_w<<<dim3(12, 16), 256, 0, stream>>>(Wv, Wvt);
  mask_flags_k<<<4096, 256, 0, stream>>>(mask, flags);
  gemm_bt<<<(M_ / 128) * (J_ / 128), 256, 0, stream>>>(Xbf, Wqkt, bqk, QKw, J_, 0);
  gemm_bt<<<(J_ / 128) * (M_ / 128), 256, 0, stream>>>(Wvt, Xbf, bv, Vtw, M_, 1);
  attn_k<<<B_ * NH_ * (S_ / 128), 256, 0, stream>>>(Xbf, QKw, Vtw, mask, flags, out);
}

// Round 8
// 475.309 us; speedup vs baseline: 1.6253x; 1.0644x over previous
//
#include <hip/hip_runtime.h>
#include <stdint.h>

#define B_ 4
#define S_ 2048
#define D_ 256
#define NH_ 12
#define M_ (B_*S_)      // 8192 rows of flattened input
#define J_ (NH_*D_)     // 3072 projection cols

typedef __bf16 bf16;
typedef __bf16 bf16x8 __attribute__((ext_vector_type(8)));
typedef __bf16 bf16x4 __attribute__((ext_vector_type(4)));
typedef __bf16 bf16x2 __attribute__((ext_vector_type(2)));
typedef float  f32x4  __attribute__((ext_vector_type(4)));

#define MFMA16(a,b,c) __builtin_amdgcn_mfma_f32_16x16x32_bf16(a,b,c,0,0,0)

__device__ __forceinline__ void g2lds16(void* l, const void* g) {
  __builtin_amdgcn_global_load_lds(
      (const __attribute__((address_space(1))) unsigned int*)g,
      (__attribute__((address_space(3))) unsigned int*)l, 16, 0, 0);
}

// ---------------- X fp32 -> bf16 ----------------
__global__ __launch_bounds__(256) void cvt_x(const float* __restrict__ in,
                                             bf16* __restrict__ out) {
  int i = blockIdx.x * 256 + threadIdx.x;
  f32x4 v = *(const f32x4*)(in + (size_t)i * 4);
  bf16x4 o;
#pragma unroll
  for (int k = 0; k < 4; ++k) o[k] = (bf16)v[k];
  *(bf16x4*)(out + (size_t)i * 4) = o;
}

// ---------------- weight transpose+cvt: W fp32 [256][3072] -> Wt bf16 [3072][256] ----------------
__global__ __launch_bounds__(256) void transpose_w(const float* __restrict__ W,
                                                   bf16* __restrict__ Wt) {
  int j  = blockIdx.x * 256 + threadIdx.x;   // 0..3071, coalesced reads over j
  int c0 = blockIdx.y * 16;
  bf16x8 v0, v1;
#pragma unroll
  for (int i = 0; i < 8; ++i) v0[i] = (bf16)W[(size_t)(c0 + i) * J_ + j];
#pragma unroll
  for (int i = 0; i < 8; ++i) v1[i] = (bf16)W[(size_t)(c0 + 8 + i) * J_ + j];
  *(bf16x8*)(Wt + (size_t)j * D_ + c0)     = v0;
  *(bf16x8*)(Wt + (size_t)j * D_ + c0 + 8) = v1;
}

// ---------------- mask tile flags: 1 if 64x64 tile is all ones ----------------
__global__ __launch_bounds__(256) void mask_flags_k(const int* __restrict__ mask,
                                                    int* __restrict__ flags) {
  int bx = blockIdx.x;                 // b*1024 + st*32 + ft
  int ft = bx & 31, st = (bx >> 5) & 31, b = bx >> 10;
  int t = threadIdx.x;
  const int4* mp4 = (const int4*)(mask + (size_t)b * S_ * S_ +
                                  (size_t)(st * 64 + (t >> 2)) * S_ + ft * 64 + (t & 3) * 16);
  bool ok = true;
#pragma unroll
  for (int i = 0; i < 4; ++i) {
    int4 v = mp4[i];
    ok &= (v.x == 1) & (v.y == 1) & (v.z == 1) & (v.w == 1);
  }
  __shared__ int flag;
  if (t == 0) flag = 1;
  __syncthreads();
  if (!ok) flag = 0;                   // benign race, all write 0
  __syncthreads();
  if (t == 0) flags[bx] = flag;
}

// ---------------- GEMM: C[M][N] = A[M][256] * Bm[N][256]^T + bias ----------------
// 128x128 tile, BK=32, 4 waves each 64x64. XOR k-chunk swizzle -> 2-way banks (free).
__global__ __launch_bounds__(256) void gemm_bt(
    const bf16* __restrict__ A, const bf16* __restrict__ Bm,
    const float* __restrict__ bias, bf16* __restrict__ C,
    int Ndim, int bias_mode)
{
  __shared__ bf16 As[128 * 32];
  __shared__ bf16 Bs[128 * 32];
  const int nbn = Ndim >> 7;
  const int bm = blockIdx.x / nbn, bn = blockIdx.x % nbn;
  const int t = threadIdx.x, w = t >> 6, l = t & 63;
  const int lane16 = l & 15, quad = l >> 4;
  const int wm = (w & 1) << 6, wn = (w >> 1) << 6;
  const int gc = ((t & 3) - (t >> 3)) & 3;
  const bf16* Ag = A + (size_t)(bm << 7) * 256 + (size_t)(t >> 2) * 256 + gc * 8;
  const bf16* Bg = Bm + (size_t)(bn << 7) * 256 + (size_t)(t >> 2) * 256 + gc * 8;
  const int rslot = ((quad + (lane16 >> 1)) & 3) * 8;
  f32x4 acc[4][4] = {};
  for (int kt = 0; kt < 256; kt += 32) {
    __syncthreads();
    g2lds16(As + (w << 9),        Ag + kt);
    g2lds16(As + 2048 + (w << 9), Ag + (size_t)64 * 256 + kt);
    g2lds16(Bs + (w << 9),        Bg + kt);
    g2lds16(Bs + 2048 + (w << 9), Bg + (size_t)64 * 256 + kt);
    __syncthreads();
    bf16x8 af[4], bfr[4];
#pragma unroll
    for (int i = 0; i < 4; ++i)
      af[i] = *(const bf16x8*)(As + (wm + i * 16 + lane16) * 32 + rslot);
#pragma unroll
    for (int i = 0; i < 4; ++i)
      bfr[i] = *(const bf16x8*)(Bs + (wn + i * 16 + lane16) * 32 + rslot);
#pragma unroll
    for (int i = 0; i < 4; ++i)
#pragma unroll
      for (int jx = 0; jx < 4; ++jx)
        acc[i][jx] = MFMA16(af[i], bfr[jx], acc[i][jx]);
  }
#pragma unroll
  for (int i = 0; i < 4; ++i)
#pragma unroll
    for (int jx = 0; jx < 4; ++jx) {
      int col = (bn << 7) + wn + jx * 16 + lane16;
#pragma unroll
      for (int r = 0; r < 4; ++r) {
        int row = (bm << 7) + wm + i * 16 + quad * 4 + r;
        float v = acc[i][jx][r] + (bias_mode ? bias[row] : bias[col]);
        C[(size_t)row * Ndim + col] = (bf16)v;
      }
    }
}

// ---------------- fused attention ----------------
// XCD-swizzled grid. Block: 4 waves, 128 s-rows; wave owns 32 s-rows end-to-end.
// TRANSPOSED QK (A=K-frag, B=Q-frag) -> St C-layout col=lane16=s, row=quad*4+r=f.
// P goes to a WAVE-PRIVATE Ps[32][40] in A-operand orientation (8 ds_write_b32,
// no barrier), PV reads 2 pf b128 + 16 vf b128 and runs full-rate K=32 MFMA over
// O[32s][256d]. ONE barrier per iteration; K/V double-buffered w/ 1-iter prefetch.
__global__ __launch_bounds__(256, 2) void attn_k(
    const bf16* __restrict__ X, const bf16* __restrict__ QK, const bf16* __restrict__ Vt,
    const int* __restrict__ mask, const int* __restrict__ flags,
    float* __restrict__ Oacc)
{
  __shared__ bf16 Ks[2][32 * 256];
  __shared__ bf16 Vs[2][256 * 32];
  __shared__ bf16 Ps[4][32 * 40];
  // XCD-aware remap: i = xcd + 8*round; round = g_sub*16 + st; group g = xcd + 8*g_sub
  const int i  = blockIdx.x;
  const int x  = i & 7, rr = i >> 3;
  const int g  = x + 8 * (rr >> 4);            // 0..47 = b*12+n
  const int st = rr & 15;                      // 128-row s-tile
  const int b  = g / 12, n = g % 12;
  const int t = threadIdx.x, w = t >> 6, l = t & 63;
  const int lane16 = l & 15, quad = l >> 4;
  const int sw = (st << 7) + (w << 5);          // wave's first of 32 s-rows
  const bf16* Xb = X + (size_t)b * S_ * D_;
  bf16x8 qf[2][8];                              // Q frags (B operand): 2 s-tiles x 256 k
#pragma unroll
  for (int ts = 0; ts < 2; ++ts)
#pragma unroll
    for (int kt = 0; kt < 8; ++kt)
      qf[ts][kt] = *(const bf16x8*)(Xb + (size_t)(sw + ts * 16 + lane16) * D_ + kt * 32 + quad * 8);
  const bf16* QKb = QK + (size_t)b * S_ * J_ + n * D_;
  const bf16* Vtb = Vt + (size_t)n * D_ * M_ + (size_t)b * S_;
  // flags row for this wave's 64-row tile: st*2 + (w>>1)
  const int* flagb = flags + (b * 32 + st * 2 + (w >> 1)) * 32;
  f32x4 oacc[2][16] = {};                       // O[32s][256d]: [ts][dt], row=s quad*4+r, col=d lane16
  float lsum[2] = {0.f, 0.f};                   // per-lane partial row sums (s=lane16)

  // staging helper: loads f-tile f0 into buffer `buf`
  auto stage = [&](int buf, int f0) {
#pragma unroll
    for (int ii = 0; ii < 4; ++ii) {
      int frow = ii * 8 + (t >> 5);
      int dc = (t & 31) ^ (frow & 7);
      g2lds16(&Ks[buf][ii * 2048 + (w << 9)], QKb + (size_t)(f0 + frow) * J_ + dc * 8);
    }
#pragma unroll
    for (int ii = 0; ii < 4; ++ii) {
      int drow = ii * 64 + (t >> 2);
      int fc = (t & 3) ^ ((drow >> 1) & 3);
      g2lds16(&Vs[buf][ii * 2048 + (w << 9)], Vtb + (size_t)drow * M_ + f0 + fc * 8);
    }
  };

  stage(0, 0);                                  // prologue prefetch
  int cur = 0;
  for (int f0 = 0; f0 < S_; f0 += 32) {
    __syncthreads();       // drains DMA(cur) (issued a full iter ago); buf cur^1 free
    if (f0 + 32 < S_) stage(cur ^ 1, f0 + 32);  // prefetch next tile under compute
    // St = K Q^T : C-layout col=lane16=s, row=quad*4+r=f.  A=kf, B=qf.
    f32x4 sfr[2][2] = {};                       // [ts][ct]
#pragma unroll
    for (int kt = 0; kt < 8; ++kt)
#pragma unroll
      for (int ct = 0; ct < 2; ++ct) {
        int fl = ct * 16 + lane16;              // A m-index rows f (read rows ct*16..)
        bf16x8 kf = *(const bf16x8*)(&Ks[cur][fl * 256 + (((kt * 4 + quad) ^ (fl & 7)) * 8)]);
        sfr[0][ct] = MFMA16(kf, qf[0][kt], sfr[0][ct]);
        sfr[1][ct] = MFMA16(kf, qf[1][kt], sfr[1][ct]);
      }
    // Now sfr[ts][ct][r] = S(s = sw+ts*16+lane16, f = f0+ct*16+quad*4+r)
    float ex[2][2][4];
    if (flagb[f0 >> 6]) {
#pragma unroll
      for (int ts = 0; ts < 2; ++ts)
#pragma unroll
        for (int ct = 0; ct < 2; ++ct)
#pragma unroll
          for (int r = 0; r < 4; ++r) ex[ts][ct][r] = __expf(sfr[ts][ct][r]);
    } else {
#pragma unroll
      for (int ts = 0; ts < 2; ++ts)
#pragma unroll
        for (int ct = 0; ct < 2; ++ct)
#pragma unroll
          for (int r = 0; r < 4; ++r) {
            int s = sw + ts * 16 + lane16, f = f0 + ct * 16 + quad * 4 + r;
            float add = (1.0f - (float)mask[(size_t)b * S_ * S_ + (size_t)s * S_ + f]) * -10000.0f;
            ex[ts][ct][r] = __expf(sfr[ts][ct][r] + add);
          }
    }
    // per-lane partial row sums (all 8 f-values belong to s=lane16 row of tile ts)
#pragma unroll
    for (int ts = 0; ts < 2; ++ts)
      lsum[ts] += ex[ts][0][0] + ex[ts][0][1] + ex[ts][0][2] + ex[ts][0][3]
                + ex[ts][1][0] + ex[ts][1][1] + ex[ts][1][2] + ex[ts][1][3];
    // P -> wave-private LDS in A-operand orientation [s=row][f=col], 8 ds_write_b32
#pragma unroll
    for (int ts = 0; ts < 2; ++ts)
#pragma unroll
      for (int ct = 0; ct < 2; ++ct) {
        int base = (ts * 16 + lane16) * 40 + ct * 16 + quad * 4;
        bf16x2 p01; p01[0] = (bf16)ex[ts][ct][0]; p01[1] = (bf16)ex[ts][ct][1];
        bf16x2 p23; p23[0] = (bf16)ex[ts][ct][2]; p23[1] = (bf16)ex[ts][ct][3];
        *(bf16x2*)(&Ps[w][base])     = p01;
        *(bf16x2*)(&Ps[w][base + 2]) = p23;
      }
    // NO barrier: Ps region is wave-private; lgkmcnt ordering suffices.
    // O[32s][256d] += P * V  (A = P[s][f] from Ps, B = Vt[d][f])
    bf16x8 pf[2];
#pragma unroll
    for (int ts = 0; ts < 2; ++ts)
      pf[ts] = *(const bf16x8*)(&Ps[w][(ts * 16 + lane16) * 40 + quad * 8]);
#pragma unroll
    for (int dt = 0; dt < 16; ++dt) {
      int dl = dt * 16 + lane16;
      bf16x8 vf = *(const bf16x8*)(&Vs[cur][dl * 32 + ((quad ^ ((dl >> 1) & 3)) * 8)]);
      oacc[0][dt] = MFMA16(pf[0], vf, oacc[0][dt]);
      oacc[1][dt] = MFMA16(pf[1], vf, oacc[1][dt]);
    }
    cur ^= 1;
  }
  // finalize row sums: reduce across quads (lanes s, s+16, s+32, s+48)
  float tot[2];
#pragma unroll
  for (int ts = 0; ts < 2; ++ts) {
    float rs = lsum[ts];
    rs += __shfl_xor(rs, 16);
    rs += __shfl_xor(rs, 32);
    tot[ts] = rs;                               // every lane: total for s=ts*16+lane16
  }
  // normalize and head-sum into fp32 output: wave writes its 32 s x 256 d
  float* Ob = Oacc + (size_t)b * S_ * D_;
#pragma unroll
  for (int ts = 0; ts < 2; ++ts)
#pragma unroll
    for (int r = 0; r < 4; ++r) {
      float inv = 1.0f / __shfl(tot[ts], quad * 4 + r, 16);  // from lane16 = quad*4+r
      int s = sw + ts * 16 + quad * 4 + r;
#pragma unroll
      for (int dt = 0; dt < 16; ++dt) {
        int d = dt * 16 + lane16;
        unsafeAtomicAdd(&Ob[(size_t)s * D_ + d], oacc[ts][dt][r] * inv);
      }
    }
}

extern "C" void kernel_launch(void* const* d_in, const int* in_sizes, int n_in,
                              void* d_out, int out_size, void* d_ws, size_t ws_size,
                              hipStream_t stream) {
  (void)in_sizes; (void)n_in; (void)out_size; (void)ws_size;
  const float* X    = (const float*)d_in[0];   // fp32 per reference
  const int*   mask = (const int*)d_in[1];
  const float* Wqk  = (const float*)d_in[2];
  const float* bqk  = (const float*)d_in[3];
  const float* Wv   = (const float*)d_in[4];
  const float* bv   = (const float*)d_in[5];
  float* out = (float*)d_out;                  // fp32 per reference output

  char* p = (char*)d_ws;
  bf16*  Xbf  = (bf16*)p;  p += (size_t)M_ * D_ * 2;      // 4.2 MB
  bf16*  Wqkt = (bf16*)p;  p += (size_t)J_ * D_ * 2;      // 1.5 MB
  bf16*  Wvt  = (bf16*)p;  p += (size_t)J_ * D_ * 2;      // 1.5 MB
  bf16*  QKw  = (bf16*)p;  p += (size_t)M_ * J_ * 2;      // 50.3 MB  [m][j]
  bf16*  Vtw  = (bf16*)p;  p += (size_t)J_ * M_ * 2;      // 50.3 MB  [j][m]
  int*   flags= (int*)p;   p += 4096 * 4;

  hipMemsetAsync(out, 0, (size_t)M_ * D_ * 4, stream);    // we accumulate into out
  cvt_x<<<(M_ * D_) / (256 * 4), 256, 0, stream>>>(X, Xbf);
  transpose_w<<<dim3(12, 16), 256, 0, stream>>>(Wqk, Wqkt);
  transpose_w<<<dim3(12, 16), 256, 0, stream>>>(Wv, Wvt);
  mask_flags_k<<<4096, 256, 0, stream>>>(mask, flags);
  gemm_bt<<<(M_ / 128) * (J_ / 128), 256, 0, stream>>>(Xbf, Wqkt, bqk, QKw, J_, 0);
  gemm_bt<<<(J_ / 128) * (M_ / 128), 256, 0, stream>>>(Wvt, Xbf, bv, Vtw, M_, 1);
  attn_k<<<B_ * NH_ * (S_ / 128), 256, 0, stream>>>(Xbf, QKw, Vtw, mask, flags, out);
}